// Round 1
// baseline (2434.552 us; speedup 1.0000x reference)
//
#include <hip/hip_runtime.h>
#include <math.h>

#define NN 4096
#define WW 12
#define HH 256
#define PP 10
#define EE 131072
#define HS 262144
#define HMASK (HS-1)

__device__ __forceinline__ float fast_tanh(float x){
  float e = __expf(2.0f*x);
  return 1.0f - 2.0f/(e+1.0f);   // exact identity (e^2x-1)/(e^2x+1)
}
__device__ __forceinline__ float fast_sigmoid(float x){
  return 1.0f/(1.0f+__expf(-x));
}

// ---------------- setup kernels ----------------

__global__ void k_init(const float* __restrict__ x, int* keys, int* midx,
                       float* deg, int* cnt, float* ring, float* hA, int* count){
  int i = blockIdx.x*256 + threadIdx.x;
  if (i < HS){ keys[i] = -1; midx[i] = -1; }
  if (i < NN){ deg[i] = 0.0f; cnt[i] = 0; }
  if (i < NN*WW) ring[i] = x[i];
  if (i < NN*HH) hA[i] = 0.0f;
  if (i == 0) *count = 0;
}

// dedupe: numpy fancy assignment => last (max-index) edge wins per (src,dst)
__global__ void k_insert(const int* __restrict__ ei, int* keys, int* midx){
  int e = blockIdx.x*256 + threadIdx.x;
  if (e >= EE) return;
  int key = ei[e]*NN + ei[EE+e];
  unsigned h = (((unsigned)key)*2654435761u >> 14) & HMASK;
  for(;;){
    int k = keys[h];
    if (k == key){ atomicMax(&midx[h], e); return; }
    if (k == -1){
      int old = atomicCAS(&keys[h], -1, key);
      if (old == -1 || old == key){ atomicMax(&midx[h], e); return; }
    }
    h = (h+1) & HMASK;
  }
}

__global__ void k_compact(const int* __restrict__ ei, const float* __restrict__ ew,
                          const int* __restrict__ keys, const int* __restrict__ midx,
                          int* wsrc, int* wdst, float* wwt,
                          float* deg, int* cnt, int* count){
  int e = blockIdx.x*256 + threadIdx.x;
  if (e >= EE) return;
  int src = ei[e], dst = ei[EE+e];
  int key = src*NN + dst;
  unsigned h = (((unsigned)key)*2654435761u >> 14) & HMASK;
  while (keys[h] != key) h = (h+1) & HMASK;
  if (midx[h] == e){            // this edge is the winner for (src,dst)
    int p = atomicAdd(count, 1);
    wsrc[p] = src; wdst[p] = dst; wwt[p] = ew[e];
    atomicAdd(&deg[src], ew[e]);   // deg = row-sum of deduped adj (self-loop +1 later)
    atomicAdd(&cnt[dst], 1);       // CSR histogram keyed by dst (L uses adj^T)
  }
}

__global__ void k_dfin(const float* __restrict__ deg, float* dval){
  int i = blockIdx.x*256 + threadIdx.x;
  if (i < NN) dval[i] = 1.0f/sqrtf(deg[i] + 1.0f);
}

__global__ void k_coeff(const int* __restrict__ wsrc, const int* __restrict__ wdst,
                        const float* __restrict__ wwt, const float* __restrict__ dval,
                        float* coef, const int* __restrict__ count){
  int p = blockIdx.x*256 + threadIdx.x;
  if (p >= *count) return;
  coef[p] = wwt[p]*dval[wsrc[p]]*dval[wdst[p]];
}

__global__ __launch_bounds__(1024) void k_scan(const int* __restrict__ cnt,
                                               int* row_start, int* fill){
  __shared__ int sd[NN];
  int tid = threadIdx.x;
  for (int i = tid; i < NN; i += 1024) sd[i] = cnt[i];
  __syncthreads();
  for (int off = 1; off < NN; off <<= 1){
    int v[4];
    #pragma unroll
    for (int r = 0; r < 4; ++r){
      int i = tid + r*1024;
      v[r] = (i >= off) ? sd[i-off] : 0;
    }
    __syncthreads();
    #pragma unroll
    for (int r = 0; r < 4; ++r) sd[tid + r*1024] += v[r];
    __syncthreads();
  }
  for (int i = tid; i < NN; i += 1024){
    int incl = sd[i];
    row_start[i+1] = incl;
    fill[i] = incl - cnt[i];   // exclusive prefix = scatter cursor
  }
  if (tid == 0) row_start[0] = 0;
}

__global__ void k_scatter(const int* __restrict__ wsrc, const int* __restrict__ wdst,
                          const float* __restrict__ coef, int* fill,
                          int* csr_src, float* csr_cf, const int* __restrict__ count){
  int p = blockIdx.x*256 + threadIdx.x;
  if (p >= *count) return;
  int pos = atomicAdd(&fill[wdst[p]], 1);
  csr_src[pos] = wsrc[p];
  csr_cf[pos] = coef[p];
}

// ---------------- per-step kernels ----------------

// ax[dst,w] = d[dst]^2 * win[dst,w] + sum_in-edges coef * win[src,w]
__global__ void k_ax(const int* __restrict__ row_start, const int* __restrict__ csr_src,
                     const float* __restrict__ csr_cf, const float* __restrict__ dval,
                     const float* __restrict__ ring, float* __restrict__ ax, int step){
  int i = blockIdx.x*256 + threadIdx.x;
  if (i >= NN*WW) return;
  int dst = i/WW, w = i - dst*WW;
  int ph = step + w; if (ph >= WW) ph -= WW;   // ring-buffer rotation
  float dv = dval[dst];
  float acc = dv*dv*ring[dst*WW + ph];
  int e1 = row_start[dst+1];
  for (int e = row_start[dst]; e < e1; ++e)
    acc += csr_cf[e]*ring[csr_src[e]*WW + ph];
  ax[i] = acc;
}

// t = relu(G @ ta_w + ta_b), G[n, w*256+c] = tanh(ax[n,w]*gcn_w[c]) computed on the fly
__global__ __launch_bounds__(256) void k_m1(const float* __restrict__ ax,
                                            const float* __restrict__ gcn_w,
                                            const float* __restrict__ ta_w,
                                            const float* __restrict__ ta_b,
                                            float* __restrict__ t_out){
  __shared__ float As[32][64];
  __shared__ float Bs[32][64];
  __shared__ float axs[64][12];
  __shared__ float gws[256];
  int tid = threadIdx.x;
  int m0 = blockIdx.y*64, n0 = blockIdx.x*64;
  gws[tid] = gcn_w[tid];
  for (int i = tid; i < 64*12; i += 256) ((float*)axs)[i] = ax[m0*WW + i];
  __syncthreads();
  float acc[4][4] = {};
  int tm = tid >> 4, tn = tid & 15;
  for (int k0 = 0; k0 < WW*HH; k0 += 32){
    #pragma unroll
    for (int r = 0; r < 2; ++r){          // B tile: 32x64
      int f = tid + r*256;
      int kk = f >> 4, n4 = (f & 15)*4;
      *(float4*)&Bs[kk][n4] = *(const float4*)&ta_w[(k0+kk)*HH + n0 + n4];
    }
    {                                      // A tile: virtual, 8 elems/thread
      int kk = tid >> 3;
      int mb = (tid & 7)*8;
      int k  = k0 + kk;
      int widx = k >> 8;
      float gw = gws[k & 255];
      #pragma unroll
      for (int i2 = 0; i2 < 8; ++i2)
        As[kk][mb+i2] = fast_tanh(axs[mb+i2][widx]*gw);
    }
    __syncthreads();
    #pragma unroll
    for (int kk = 0; kk < 32; ++kk){
      float4 a4 = *(float4*)&As[kk][tm*4];
      float4 b4 = *(float4*)&Bs[kk][tn*4];
      float a[4] = {a4.x,a4.y,a4.z,a4.w};
      float b[4] = {b4.x,b4.y,b4.z,b4.w};
      #pragma unroll
      for (int i = 0; i < 4; ++i)
        #pragma unroll
        for (int j = 0; j < 4; ++j)
          acc[i][j] = fmaf(a[i], b[j], acc[i][j]);
    }
    __syncthreads();
  }
  #pragma unroll
  for (int i = 0; i < 4; ++i){
    int row = m0 + tm*4 + i;
    #pragma unroll
    for (int j = 0; j < 4; ++j){
      int col = n0 + tn*4 + j;
      float v = acc[i][j] + ta_b[col];
      t_out[row*HH + col] = v > 0.0f ? v : 0.0f;
    }
  }
}

// fused GRU: 6 dot products per (n,c) + gate nonlinearities; gx/gh never materialized
__global__ __launch_bounds__(256) void k_gru(const float* __restrict__ t_in,
                                             const float* __restrict__ h_in,
                                             const float* __restrict__ w_ih,
                                             const float* __restrict__ w_hh,
                                             const float* __restrict__ b_ih,
                                             const float* __restrict__ b_hh,
                                             float* __restrict__ h_out){
  __shared__ float Ts[32][64];
  __shared__ float Hs[32][64];
  __shared__ float Wx[3][32][32];
  __shared__ float Wh[3][32][32];
  int tid = threadIdx.x;
  int m0 = blockIdx.y*64, n0 = blockIdx.x*32;
  int tm = tid >> 4, tn = tid & 15;
  float accx[3][4][2] = {};
  float acch[3][4][2] = {};
  for (int k0 = 0; k0 < HH; k0 += 32){
    #pragma unroll
    for (int r = 0; r < 2; ++r){           // stage T,H tiles (transposed)
      int f = tid + r*256;
      int m = f >> 3, kq = (f & 7)*4;
      float4 v = *(const float4*)&t_in[(m0+m)*HH + k0 + kq];
      Ts[kq+0][m]=v.x; Ts[kq+1][m]=v.y; Ts[kq+2][m]=v.z; Ts[kq+3][m]=v.w;
      float4 u = *(const float4*)&h_in[(m0+m)*HH + k0 + kq];
      Hs[kq+0][m]=u.x; Hs[kq+1][m]=u.y; Hs[kq+2][m]=u.z; Hs[kq+3][m]=u.w;
    }
    #pragma unroll
    for (int r = 0; r < 3; ++r){           // stage 3-gate weight slices
      int f = tid + r*256;
      int g = f >> 8, rem = f & 255;
      int n = rem >> 3, kq = (rem & 7)*4;
      float4 v = *(const float4*)&w_ih[(g*HH + n0 + n)*HH + k0 + kq];
      Wx[g][kq+0][n]=v.x; Wx[g][kq+1][n]=v.y; Wx[g][kq+2][n]=v.z; Wx[g][kq+3][n]=v.w;
      float4 u = *(const float4*)&w_hh[(g*HH + n0 + n)*HH + k0 + kq];
      Wh[g][kq+0][n]=u.x; Wh[g][kq+1][n]=u.y; Wh[g][kq+2][n]=u.z; Wh[g][kq+3][n]=u.w;
    }
    __syncthreads();
    #pragma unroll
    for (int kk = 0; kk < 32; ++kk){
      float4 tf4 = *(float4*)&Ts[kk][tm*4];
      float4 hf4 = *(float4*)&Hs[kk][tm*4];
      float tf[4] = {tf4.x,tf4.y,tf4.z,tf4.w};
      float hf[4] = {hf4.x,hf4.y,hf4.z,hf4.w};
      #pragma unroll
      for (int g = 0; g < 3; ++g){
        float2 wx2 = *(float2*)&Wx[g][kk][tn*2];
        float2 wh2 = *(float2*)&Wh[g][kk][tn*2];
        float wx[2] = {wx2.x, wx2.y};
        float wh[2] = {wh2.x, wh2.y};
        #pragma unroll
        for (int i = 0; i < 4; ++i)
          #pragma unroll
          for (int j = 0; j < 2; ++j){
            accx[g][i][j] = fmaf(tf[i], wx[j], accx[g][i][j]);
            acch[g][i][j] = fmaf(hf[i], wh[j], acch[g][i][j]);
          }
      }
    }
    __syncthreads();
  }
  #pragma unroll
  for (int i = 0; i < 4; ++i){
    int row = m0 + tm*4 + i;
    #pragma unroll
    for (int j = 0; j < 2; ++j){
      int col = n0 + tn*2 + j;
      float xr = accx[0][i][j] + b_ih[col];
      float xz = accx[1][i][j] + b_ih[col+HH];
      float xn = accx[2][i][j] + b_ih[col+2*HH];
      float hr = acch[0][i][j] + b_hh[col];
      float hz = acch[1][i][j] + b_hh[col+HH];
      float hn = acch[2][i][j] + b_hh[col+2*HH];
      float r  = fast_sigmoid(xr + hr);
      float z  = fast_sigmoid(xz + hz);
      float nn = fast_tanh(xn + r*hn);
      float hv = h_in[row*HH + col];
      h_out[row*HH + col] = (1.0f - z)*nn + z*hv;
    }
  }
}

// pred = h2 @ out_w + out_b; write output column s and the ring slot
__global__ __launch_bounds__(256) void k_pred(const float* __restrict__ h2,
                                              const float* __restrict__ out_w,
                                              const float* __restrict__ out_b,
                                              float* __restrict__ out,
                                              float* __restrict__ ring, int step){
  int gtid = blockIdx.x*256 + threadIdx.x;
  int row = gtid >> 6;
  int lane = threadIdx.x & 63;
  if (row >= NN) return;
  const float* hr = h2 + row*HH;
  float s = 0.0f;
  #pragma unroll
  for (int c = lane; c < HH; c += 64) s += hr[c]*out_w[c];
  #pragma unroll
  for (int off = 32; off > 0; off >>= 1) s += __shfl_down(s, off, 64);
  if (lane == 0){
    float p = s + out_b[0];
    out[row*PP + step] = p;
    ring[row*WW + step] = p;   // step < 12, slot step is the one rotated out
  }
}

// ---------------- launcher ----------------

extern "C" void kernel_launch(void* const* d_in, const int* in_sizes, int n_in,
                              void* d_out, int out_size, void* d_ws, size_t ws_size,
                              hipStream_t stream){
  const float* x     = (const float*)d_in[0];
  const int*   ei    = (const int*)  d_in[1];
  const float* ew    = (const float*)d_in[2];
  const float* gcn_w = (const float*)d_in[3];
  const float* ta_w  = (const float*)d_in[4];
  const float* ta_b  = (const float*)d_in[5];
  const float* w_ih  = (const float*)d_in[6];
  const float* w_hh  = (const float*)d_in[7];
  const float* b_ih  = (const float*)d_in[8];
  const float* b_hh  = (const float*)d_in[9];
  const float* out_w = (const float*)d_in[10];
  const float* out_b = (const float*)d_in[11];
  float* out = (float*)d_out;

  char* p = (char*)d_ws;
  int*   keys    = (int*)p;   p += (size_t)HS*4;
  int*   midx    = (int*)p;   p += (size_t)HS*4;
  int*   wsrc    = (int*)p;   p += (size_t)EE*4;
  int*   wdst    = (int*)p;   p += (size_t)EE*4;
  float* wwt     = (float*)p; p += (size_t)EE*4;
  float* coef    = (float*)p; p += (size_t)EE*4;
  int*   csr_src = (int*)p;   p += (size_t)EE*4;
  float* csr_cf  = (float*)p; p += (size_t)EE*4;
  float* deg     = (float*)p; p += (size_t)NN*4;
  float* dval    = (float*)p; p += (size_t)NN*4;
  int*   cnt     = (int*)p;   p += (size_t)NN*4;
  int*   fill    = (int*)p;   p += (size_t)NN*4;
  int*   rowst   = (int*)p;   p += (size_t)(NN+64)*4;
  int*   count   = (int*)p;   p += 256;
  float* ring    = (float*)p; p += (size_t)NN*WW*4;
  float* ax      = (float*)p; p += (size_t)NN*WW*4;
  float* tbuf    = (float*)p; p += (size_t)NN*HH*4;
  float* hA      = (float*)p; p += (size_t)NN*HH*4;
  float* hB      = (float*)p; p += (size_t)NN*HH*4;

  k_init   <<<(NN*HH)/256, 256, 0, stream>>>(x, keys, midx, deg, cnt, ring, hA, count);
  k_insert <<<EE/256, 256, 0, stream>>>(ei, keys, midx);
  k_compact<<<EE/256, 256, 0, stream>>>(ei, ew, keys, midx, wsrc, wdst, wwt, deg, cnt, count);
  k_dfin   <<<NN/256, 256, 0, stream>>>(deg, dval);
  k_coeff  <<<EE/256, 256, 0, stream>>>(wsrc, wdst, wwt, dval, coef, count);
  k_scan   <<<1, 1024, 0, stream>>>(cnt, rowst, fill);
  k_scatter<<<EE/256, 256, 0, stream>>>(wsrc, wdst, coef, fill, csr_src, csr_cf, count);

  for (int s = 0; s < PP; ++s){
    float* h_in  = (s & 1) ? hB : hA;
    float* h_out = (s & 1) ? hA : hB;
    k_ax  <<<(NN*WW)/256, 256, 0, stream>>>(rowst, csr_src, csr_cf, dval, ring, ax, s);
    k_m1  <<<dim3(HH/64, NN/64), 256, 0, stream>>>(ax, gcn_w, ta_w, ta_b, tbuf);
    k_gru <<<dim3(HH/32, NN/64), 256, 0, stream>>>(tbuf, h_in, w_ih, w_hh, b_ih, b_hh, h_out);
    k_pred<<<NN/4, 256, 0, stream>>>(h_out, out_w, out_b, out, ring, s);
  }
}

// Round 2
// 1002.016 us; speedup vs baseline: 2.4297x; 2.4297x over previous
//
#include <hip/hip_runtime.h>
#include <math.h>

#define NN 4096
#define WW 12
#define HH 256
#define PP 10
#define EE 131072
#define HS 262144
#define HMASK (HS-1)
#define TS 1024          // table intervals (1025 sample points)
#define TA 12.0f         // table half-domain: a in [-TA, TA]

__device__ __forceinline__ float fast_tanh(float x){
  float e = __expf(2.0f*x);
  return 1.0f - 2.0f/(e+1.0f);   // exact identity (e^2x-1)/(e^2x+1)
}
__device__ __forceinline__ float fast_sigmoid(float x){
  return 1.0f/(1.0f+__expf(-x));
}

// ---------------- setup kernels ----------------

__global__ void k_init(const float* __restrict__ x, int* keys, int* midx,
                       float* deg, int* cnt, float* ring, float* hA, int* count){
  int i = blockIdx.x*256 + threadIdx.x;
  if (i < HS){ keys[i] = -1; midx[i] = -1; }
  if (i < NN){ deg[i] = 0.0f; cnt[i] = 0; }
  if (i < NN*WW) ring[i] = x[i];
  if (i < NN*HH) hA[i] = 0.0f;
  if (i == 0) *count = 0;
}

// dedupe: numpy fancy assignment => last (max-index) edge wins per (src,dst)
__global__ void k_insert(const int* __restrict__ ei, int* keys, int* midx){
  int e = blockIdx.x*256 + threadIdx.x;
  if (e >= EE) return;
  int key = ei[e]*NN + ei[EE+e];
  unsigned h = (((unsigned)key)*2654435761u >> 14) & HMASK;
  for(;;){
    int k = keys[h];
    if (k == key){ atomicMax(&midx[h], e); return; }
    if (k == -1){
      int old = atomicCAS(&keys[h], -1, key);
      if (old == -1 || old == key){ atomicMax(&midx[h], e); return; }
    }
    h = (h+1) & HMASK;
  }
}

__global__ void k_compact(const int* __restrict__ ei, const float* __restrict__ ew,
                          const int* __restrict__ keys, const int* __restrict__ midx,
                          int* wsrc, int* wdst, float* wwt,
                          float* deg, int* cnt, int* count){
  int e = blockIdx.x*256 + threadIdx.x;
  if (e >= EE) return;
  int src = ei[e], dst = ei[EE+e];
  int key = src*NN + dst;
  unsigned h = (((unsigned)key)*2654435761u >> 14) & HMASK;
  while (keys[h] != key) h = (h+1) & HMASK;
  if (midx[h] == e){            // this edge is the winner for (src,dst)
    int p = atomicAdd(count, 1);
    wsrc[p] = src; wdst[p] = dst; wwt[p] = ew[e];
    atomicAdd(&deg[src], ew[e]);   // deg = row-sum of deduped adj (self-loop +1 later)
    atomicAdd(&cnt[dst], 1);       // CSR histogram keyed by dst (L uses adj^T)
  }
}

__global__ void k_dfin(const float* __restrict__ deg, float* dval){
  int i = blockIdx.x*256 + threadIdx.x;
  if (i < NN) dval[i] = 1.0f/sqrtf(deg[i] + 1.0f);
}

__global__ void k_coeff(const int* __restrict__ wsrc, const int* __restrict__ wdst,
                        const float* __restrict__ wwt, const float* __restrict__ dval,
                        float* coef, const int* __restrict__ count){
  int p = blockIdx.x*256 + threadIdx.x;
  if (p >= *count) return;
  coef[p] = wwt[p]*dval[wsrc[p]]*dval[wdst[p]];
}

__global__ __launch_bounds__(1024) void k_scan(const int* __restrict__ cnt,
                                               int* row_start, int* fill){
  __shared__ int sd[NN];
  int tid = threadIdx.x;
  for (int i = tid; i < NN; i += 1024) sd[i] = cnt[i];
  __syncthreads();
  for (int off = 1; off < NN; off <<= 1){
    int v[4];
    #pragma unroll
    for (int r = 0; r < 4; ++r){
      int i = tid + r*1024;
      v[r] = (i >= off) ? sd[i-off] : 0;
    }
    __syncthreads();
    #pragma unroll
    for (int r = 0; r < 4; ++r) sd[tid + r*1024] += v[r];
    __syncthreads();
  }
  for (int i = tid; i < NN; i += 1024){
    int incl = sd[i];
    row_start[i+1] = incl;
    fill[i] = incl - cnt[i];   // exclusive prefix = scatter cursor
  }
  if (tid == 0) row_start[0] = 0;
}

__global__ void k_scatter(const int* __restrict__ wsrc, const int* __restrict__ wdst,
                          const float* __restrict__ coef, int* fill,
                          int* csr_src, float* csr_cf, const int* __restrict__ count){
  int p = blockIdx.x*256 + threadIdx.x;
  if (p >= *count) return;
  int pos = atomicAdd(&fill[wdst[p]], 1);
  csr_src[pos] = wsrc[p];
  csr_cf[pos] = coef[p];
}

// table build: tab[w][s][h] = sum_c tanh(a_s*gw[c]) * ta_w[w*256+c, h]
// 12 GEMMs of (1088x256)@(256x256), run ONCE per launch
__global__ __launch_bounds__(256) void k_tab(const float* __restrict__ gcn_w,
                                             const float* __restrict__ ta_w,
                                             float* __restrict__ tab){
  __shared__ float As[32][64];
  __shared__ float Bs[32][64];
  __shared__ float gws[256];
  int tid = threadIdx.x;
  int n0 = blockIdx.x*64;        // h tile
  int m0 = blockIdx.y*64;        // sample tile
  int w  = blockIdx.z;
  gws[tid] = gcn_w[tid];
  __syncthreads();
  float acc[4][4] = {};
  int tm = tid >> 4, tn = tid & 15;
  const float astep = 2.0f*TA/TS;
  for (int k0 = 0; k0 < 256; k0 += 32){
    #pragma unroll
    for (int r = 0; r < 2; ++r){
      int f = tid + r*256;
      int kk = f >> 4, n4 = (f & 15)*4;
      *(float4*)&Bs[kk][n4] = *(const float4*)&ta_w[(w*256 + k0+kk)*HH + n0 + n4];
    }
    {
      int kk = tid >> 3;
      int mb = (tid & 7)*8;
      float gw = gws[k0 + kk];
      #pragma unroll
      for (int i2 = 0; i2 < 8; ++i2){
        float a = -TA + (float)(m0 + mb + i2)*astep;
        As[kk][mb+i2] = fast_tanh(a*gw);
      }
    }
    __syncthreads();
    #pragma unroll
    for (int kk = 0; kk < 32; ++kk){
      float4 a4 = *(float4*)&As[kk][tm*4];
      float4 b4 = *(float4*)&Bs[kk][tn*4];
      float a[4] = {a4.x,a4.y,a4.z,a4.w};
      float b[4] = {b4.x,b4.y,b4.z,b4.w};
      #pragma unroll
      for (int i = 0; i < 4; ++i)
        #pragma unroll
        for (int j = 0; j < 4; ++j)
          acc[i][j] = fmaf(a[i], b[j], acc[i][j]);
    }
    __syncthreads();
  }
  #pragma unroll
  for (int i = 0; i < 4; ++i){
    int row = m0 + tm*4 + i;
    if (row <= TS){
      #pragma unroll
      for (int j = 0; j < 4; ++j)
        tab[((size_t)w*(TS+1) + row)*HH + n0 + tn*4 + j] = acc[i][j];
    }
  }
}

// ---------------- per-step kernels ----------------

// ax[dst,w] = d[dst]^2 * win[dst,w] + sum_in-edges coef * win[src,w]
__global__ void k_ax(const int* __restrict__ row_start, const int* __restrict__ csr_src,
                     const float* __restrict__ csr_cf, const float* __restrict__ dval,
                     const float* __restrict__ ring, float* __restrict__ ax, int step){
  int i = blockIdx.x*256 + threadIdx.x;
  if (i >= NN*WW) return;
  int dst = i/WW, w = i - dst*WW;
  int ph = step + w; if (ph >= WW) ph -= WW;   // ring-buffer rotation
  float dv = dval[dst];
  float acc = dv*dv*ring[dst*WW + ph];
  int e1 = row_start[dst+1];
  for (int e = row_start[dst]; e < e1; ++e)
    acc += csr_cf[e]*ring[csr_src[e]*WW + ph];
  ax[i] = acc;
}

// t[n,h] = relu(ta_b[h] + sum_w lerp(tab[w], ax[n,w])[h])  -- replaces the 6.4GF GEMM
__global__ __launch_bounds__(256) void k_t(const float* __restrict__ ax,
                                           const float* __restrict__ tab,
                                           const float* __restrict__ ta_b,
                                           float* __restrict__ t_out){
  __shared__ int   sidx[8][12];
  __shared__ float sfrac[8][12];
  int tid = threadIdx.x;
  int n0 = blockIdx.x*8;
  if (tid < 96){
    int r = tid/12, w = tid - r*12;
    float u = (ax[(n0+r)*WW + w] + TA) * ((float)TS/(2.0f*TA));
    u = fminf(fmaxf(u, 0.0f), (float)TS - 0.0005f);
    int i = (int)u;
    sidx[r][w] = i;
    sfrac[r][w] = u - (float)i;
  }
  __syncthreads();
  float tb = ta_b[tid];
  #pragma unroll
  for (int r = 0; r < 8; ++r){
    float acc = tb;
    #pragma unroll
    for (int w = 0; w < 12; ++w){
      const float* p = tab + ((size_t)w*(TS+1) + sidx[r][w])*HH + tid;
      float v0 = p[0], v1 = p[HH];
      acc += v0 + sfrac[r][w]*(v1 - v0);
    }
    t_out[(n0+r)*HH + tid] = acc > 0.0f ? acc : 0.0f;
  }
}

// fused GRU: 6 dot products per (n,c) + gate nonlinearities; gx/gh never materialized
__global__ __launch_bounds__(256) void k_gru(const float* __restrict__ t_in,
                                             const float* __restrict__ h_in,
                                             const float* __restrict__ w_ih,
                                             const float* __restrict__ w_hh,
                                             const float* __restrict__ b_ih,
                                             const float* __restrict__ b_hh,
                                             float* __restrict__ h_out){
  __shared__ float Ts[32][64];
  __shared__ float Hs[32][64];
  __shared__ float Wx[3][32][32];
  __shared__ float Wh[3][32][32];
  int tid = threadIdx.x;
  int m0 = blockIdx.y*64, n0 = blockIdx.x*32;
  int tm = tid >> 4, tn = tid & 15;
  float accx[3][4][2] = {};
  float acch[3][4][2] = {};
  for (int k0 = 0; k0 < HH; k0 += 32){
    #pragma unroll
    for (int r = 0; r < 2; ++r){           // stage T,H tiles (transposed)
      int f = tid + r*256;
      int m = f >> 3, kq = (f & 7)*4;
      float4 v = *(const float4*)&t_in[(m0+m)*HH + k0 + kq];
      Ts[kq+0][m]=v.x; Ts[kq+1][m]=v.y; Ts[kq+2][m]=v.z; Ts[kq+3][m]=v.w;
      float4 u = *(const float4*)&h_in[(m0+m)*HH + k0 + kq];
      Hs[kq+0][m]=u.x; Hs[kq+1][m]=u.y; Hs[kq+2][m]=u.z; Hs[kq+3][m]=u.w;
    }
    #pragma unroll
    for (int r = 0; r < 3; ++r){           // stage 3-gate weight slices
      int f = tid + r*256;
      int g = f >> 8, rem = f & 255;
      int n = rem >> 3, kq = (rem & 7)*4;
      float4 v = *(const float4*)&w_ih[(g*HH + n0 + n)*HH + k0 + kq];
      Wx[g][kq+0][n]=v.x; Wx[g][kq+1][n]=v.y; Wx[g][kq+2][n]=v.z; Wx[g][kq+3][n]=v.w;
      float4 u = *(const float4*)&w_hh[(g*HH + n0 + n)*HH + k0 + kq];
      Wh[g][kq+0][n]=u.x; Wh[g][kq+1][n]=u.y; Wh[g][kq+2][n]=u.z; Wh[g][kq+3][n]=u.w;
    }
    __syncthreads();
    #pragma unroll
    for (int kk = 0; kk < 32; ++kk){
      float4 tf4 = *(float4*)&Ts[kk][tm*4];
      float4 hf4 = *(float4*)&Hs[kk][tm*4];
      float tf[4] = {tf4.x,tf4.y,tf4.z,tf4.w};
      float hf[4] = {hf4.x,hf4.y,hf4.z,hf4.w};
      #pragma unroll
      for (int g = 0; g < 3; ++g){
        float2 wx2 = *(float2*)&Wx[g][kk][tn*2];
        float2 wh2 = *(float2*)&Wh[g][kk][tn*2];
        float wx[2] = {wx2.x, wx2.y};
        float wh[2] = {wh2.x, wh2.y};
        #pragma unroll
        for (int i = 0; i < 4; ++i)
          #pragma unroll
          for (int j = 0; j < 2; ++j){
            accx[g][i][j] = fmaf(tf[i], wx[j], accx[g][i][j]);
            acch[g][i][j] = fmaf(hf[i], wh[j], acch[g][i][j]);
          }
      }
    }
    __syncthreads();
  }
  #pragma unroll
  for (int i = 0; i < 4; ++i){
    int row = m0 + tm*4 + i;
    #pragma unroll
    for (int j = 0; j < 2; ++j){
      int col = n0 + tn*2 + j;
      float xr = accx[0][i][j] + b_ih[col];
      float xz = accx[1][i][j] + b_ih[col+HH];
      float xn = accx[2][i][j] + b_ih[col+2*HH];
      float hr = acch[0][i][j] + b_hh[col];
      float hz = acch[1][i][j] + b_hh[col+HH];
      float hn = acch[2][i][j] + b_hh[col+2*HH];
      float r  = fast_sigmoid(xr + hr);
      float z  = fast_sigmoid(xz + hz);
      float nn = fast_tanh(xn + r*hn);
      float hv = h_in[row*HH + col];
      h_out[row*HH + col] = (1.0f - z)*nn + z*hv;
    }
  }
}

// pred = h2 @ out_w + out_b; write output column s and the ring slot
__global__ __launch_bounds__(256) void k_pred(const float* __restrict__ h2,
                                              const float* __restrict__ out_w,
                                              const float* __restrict__ out_b,
                                              float* __restrict__ out,
                                              float* __restrict__ ring, int step){
  int gtid = blockIdx.x*256 + threadIdx.x;
  int row = gtid >> 6;
  int lane = threadIdx.x & 63;
  if (row >= NN) return;
  const float* hr = h2 + row*HH;
  float s = 0.0f;
  #pragma unroll
  for (int c = lane; c < HH; c += 64) s += hr[c]*out_w[c];
  #pragma unroll
  for (int off = 32; off > 0; off >>= 1) s += __shfl_down(s, off, 64);
  if (lane == 0){
    float p = s + out_b[0];
    out[row*PP + step] = p;
    ring[row*WW + step] = p;   // step < 12, slot step is the one rotated out
  }
}

// ---------------- launcher ----------------

extern "C" void kernel_launch(void* const* d_in, const int* in_sizes, int n_in,
                              void* d_out, int out_size, void* d_ws, size_t ws_size,
                              hipStream_t stream){
  const float* x     = (const float*)d_in[0];
  const int*   ei    = (const int*)  d_in[1];
  const float* ew    = (const float*)d_in[2];
  const float* gcn_w = (const float*)d_in[3];
  const float* ta_w  = (const float*)d_in[4];
  const float* ta_b  = (const float*)d_in[5];
  const float* w_ih  = (const float*)d_in[6];
  const float* w_hh  = (const float*)d_in[7];
  const float* b_ih  = (const float*)d_in[8];
  const float* b_hh  = (const float*)d_in[9];
  const float* out_w = (const float*)d_in[10];
  const float* out_b = (const float*)d_in[11];
  float* out = (float*)d_out;

  // tab occupies the front of ws; the setup-only buffers (hash + edge temps,
  // 4.5 MB) ALIAS into tab's 12.6 MB region — they are dead before k_tab runs
  // (stream-ordered), so the overlap is safe and deterministic.
  char* base = (char*)d_ws;
  float* tab = (float*)base;                               // 12*(TS+1)*HH*4 = 12.6 MB
  char* p = base;
  int*   keys    = (int*)p;   p += (size_t)HS*4;           // |
  int*   midx    = (int*)p;   p += (size_t)HS*4;           // | setup-only,
  int*   wsrc    = (int*)p;   p += (size_t)EE*4;           // | aliased inside tab
  int*   wdst    = (int*)p;   p += (size_t)EE*4;           // |
  float* wwt     = (float*)p; p += (size_t)EE*4;           // |
  float* coef    = (float*)p; p += (size_t)EE*4;           // |
  p = base + (size_t)12*(TS+1)*HH*4;                       // end of tab
  int*   csr_src = (int*)p;   p += (size_t)EE*4;
  float* csr_cf  = (float*)p; p += (size_t)EE*4;
  float* deg     = (float*)p; p += (size_t)NN*4;
  float* dval    = (float*)p; p += (size_t)NN*4;
  int*   cnt     = (int*)p;   p += (size_t)NN*4;
  int*   fill    = (int*)p;   p += (size_t)NN*4;
  int*   rowst   = (int*)p;   p += (size_t)(NN+64)*4;
  int*   count   = (int*)p;   p += 256;
  float* ring    = (float*)p; p += (size_t)NN*WW*4;
  float* ax      = (float*)p; p += (size_t)NN*WW*4;
  float* tbuf    = (float*)p; p += (size_t)NN*HH*4;
  float* hA      = (float*)p; p += (size_t)NN*HH*4;
  float* hB      = (float*)p; p += (size_t)NN*HH*4;

  k_init   <<<(NN*HH)/256, 256, 0, stream>>>(x, keys, midx, deg, cnt, ring, hA, count);
  k_insert <<<EE/256, 256, 0, stream>>>(ei, keys, midx);
  k_compact<<<EE/256, 256, 0, stream>>>(ei, ew, keys, midx, wsrc, wdst, wwt, deg, cnt, count);
  k_dfin   <<<NN/256, 256, 0, stream>>>(deg, dval);
  k_coeff  <<<EE/256, 256, 0, stream>>>(wsrc, wdst, wwt, dval, coef, count);
  k_scan   <<<1, 1024, 0, stream>>>(cnt, rowst, fill);
  k_scatter<<<EE/256, 256, 0, stream>>>(wsrc, wdst, coef, fill, csr_src, csr_cf, count);
  // after k_scatter the aliased setup buffers are dead; build the table over them
  k_tab    <<<dim3(HH/64, (TS+64)/64, WW), 256, 0, stream>>>(gcn_w, ta_w, tab);

  for (int s = 0; s < PP; ++s){
    float* h_in  = (s & 1) ? hB : hA;
    float* h_out = (s & 1) ? hA : hB;
    k_ax  <<<(NN*WW)/256, 256, 0, stream>>>(rowst, csr_src, csr_cf, dval, ring, ax, s);
    k_t   <<<NN/8, 256, 0, stream>>>(ax, tab, ta_b, tbuf);
    k_gru <<<dim3(HH/32, NN/64), 256, 0, stream>>>(tbuf, h_in, w_ih, w_hh, b_ih, b_hh, h_out);
    k_pred<<<NN/4, 256, 0, stream>>>(h_out, out_w, out_b, out, ring, s);
  }
}

// Round 3
// 632.114 us; speedup vs baseline: 3.8514x; 1.5852x over previous
//
#include <hip/hip_runtime.h>
#include <math.h>

#define NN 4096
#define WW 12
#define HH 256
#define PP 10
#define EE 131072
#define HS 262144
#define HMASK (HS-1)
#define TS 1024          // table intervals (1025 sample points)
#define TA 12.0f         // table half-domain: a in [-TA, TA]

typedef __attribute__((ext_vector_type(8))) short short8v;   // 8 x bf16 (A/B frag)
typedef __attribute__((ext_vector_type(4))) float f32x4;     // C/D frag

__device__ __forceinline__ float fast_tanh(float x){
  float e = __expf(2.0f*x);
  return 1.0f - 2.0f/(e+1.0f);   // exact identity (e^2x-1)/(e^2x+1)
}
__device__ __forceinline__ float fast_sigmoid(float x){
  return 1.0f/(1.0f+__expf(-x));
}
__device__ __forceinline__ unsigned short f2bf(float f){     // RNE fp32->bf16
  union{float f; unsigned u;} v; v.f = f;
  unsigned r = v.u + 0x7FFF + ((v.u>>16)&1);
  return (unsigned short)(r>>16);
}
__device__ __forceinline__ float bf2f(unsigned short h){
  union{unsigned u; float f;} v; v.u = ((unsigned)h)<<16; return v.f;
}

// ---------------- setup kernels ----------------

__global__ void k_init(const float* __restrict__ x, int* keys, int* midx,
                       float* deg, int* cnt, float* ring, float* hA, int* count){
  int i = blockIdx.x*256 + threadIdx.x;
  if (i < HS){ keys[i] = -1; midx[i] = -1; }
  if (i < NN){ deg[i] = 0.0f; cnt[i] = 0; }
  if (i < NN*WW) ring[i] = x[i];
  if (i < NN*HH) hA[i] = 0.0f;
  if (i == 0) *count = 0;
}

// dedupe: numpy fancy assignment => last (max-index) edge wins per (src,dst)
__global__ void k_insert(const int* __restrict__ ei, int* keys, int* midx){
  int e = blockIdx.x*256 + threadIdx.x;
  if (e >= EE) return;
  int key = ei[e]*NN + ei[EE+e];
  unsigned h = (((unsigned)key)*2654435761u >> 14) & HMASK;
  for(;;){
    int k = keys[h];
    if (k == key){ atomicMax(&midx[h], e); return; }
    if (k == -1){
      int old = atomicCAS(&keys[h], -1, key);
      if (old == -1 || old == key){ atomicMax(&midx[h], e); return; }
    }
    h = (h+1) & HMASK;
  }
}

__global__ void k_compact(const int* __restrict__ ei, const float* __restrict__ ew,
                          const int* __restrict__ keys, const int* __restrict__ midx,
                          int* wsrc, int* wdst, float* wwt,
                          float* deg, int* cnt, int* count){
  int e = blockIdx.x*256 + threadIdx.x;
  if (e >= EE) return;
  int src = ei[e], dst = ei[EE+e];
  int key = src*NN + dst;
  unsigned h = (((unsigned)key)*2654435761u >> 14) & HMASK;
  while (keys[h] != key) h = (h+1) & HMASK;
  if (midx[h] == e){            // this edge is the winner for (src,dst)
    int p = atomicAdd(count, 1);
    wsrc[p] = src; wdst[p] = dst; wwt[p] = ew[e];
    atomicAdd(&deg[src], ew[e]);   // deg = row-sum of deduped adj (self-loop +1 later)
    atomicAdd(&cnt[dst], 1);       // CSR histogram keyed by dst (L uses adj^T)
  }
}

__global__ void k_dfin(const float* __restrict__ deg, float* dval){
  int i = blockIdx.x*256 + threadIdx.x;
  if (i < NN) dval[i] = 1.0f/sqrtf(deg[i] + 1.0f);
}

__global__ void k_coeff(const int* __restrict__ wsrc, const int* __restrict__ wdst,
                        const float* __restrict__ wwt, const float* __restrict__ dval,
                        float* coef, const int* __restrict__ count){
  int p = blockIdx.x*256 + threadIdx.x;
  if (p >= *count) return;
  coef[p] = wwt[p]*dval[wsrc[p]]*dval[wdst[p]];
}

__global__ __launch_bounds__(1024) void k_scan(const int* __restrict__ cnt,
                                               int* row_start, int* fill){
  __shared__ int sd[NN];
  int tid = threadIdx.x;
  for (int i = tid; i < NN; i += 1024) sd[i] = cnt[i];
  __syncthreads();
  for (int off = 1; off < NN; off <<= 1){
    int v[4];
    #pragma unroll
    for (int r = 0; r < 4; ++r){
      int i = tid + r*1024;
      v[r] = (i >= off) ? sd[i-off] : 0;
    }
    __syncthreads();
    #pragma unroll
    for (int r = 0; r < 4; ++r) sd[tid + r*1024] += v[r];
    __syncthreads();
  }
  for (int i = tid; i < NN; i += 1024){
    int incl = sd[i];
    row_start[i+1] = incl;
    fill[i] = incl - cnt[i];   // exclusive prefix = scatter cursor
  }
  if (tid == 0) row_start[0] = 0;
}

__global__ void k_scatter(const int* __restrict__ wsrc, const int* __restrict__ wdst,
                          const float* __restrict__ coef, int* fill,
                          int* csr_src, float* csr_cf, const int* __restrict__ count){
  int p = blockIdx.x*256 + threadIdx.x;
  if (p >= *count) return;
  int pos = atomicAdd(&fill[wdst[p]], 1);
  csr_src[pos] = wsrc[p];
  csr_cf[pos] = coef[p];
}

// table build: tab[w][s][h] = sum_c tanh(a_s*gw[c]) * ta_w[w*256+c, h]
__global__ __launch_bounds__(256) void k_tab(const float* __restrict__ gcn_w,
                                             const float* __restrict__ ta_w,
                                             float* __restrict__ tab){
  __shared__ float As[32][64];
  __shared__ float Bs[32][64];
  __shared__ float gws[256];
  int tid = threadIdx.x;
  int n0 = blockIdx.x*64;        // h tile
  int m0 = blockIdx.y*64;        // sample tile
  int w  = blockIdx.z;
  gws[tid] = gcn_w[tid];
  __syncthreads();
  float acc[4][4] = {};
  int tm = tid >> 4, tn = tid & 15;
  const float astep = 2.0f*TA/TS;
  for (int k0 = 0; k0 < 256; k0 += 32){
    #pragma unroll
    for (int r = 0; r < 2; ++r){
      int f = tid + r*256;
      int kk = f >> 4, n4 = (f & 15)*4;
      *(float4*)&Bs[kk][n4] = *(const float4*)&ta_w[(w*256 + k0+kk)*HH + n0 + n4];
    }
    {
      int kk = tid >> 3;
      int mb = (tid & 7)*8;
      float gw = gws[k0 + kk];
      #pragma unroll
      for (int i2 = 0; i2 < 8; ++i2){
        float a = -TA + (float)(m0 + mb + i2)*astep;
        As[kk][mb+i2] = fast_tanh(a*gw);
      }
    }
    __syncthreads();
    #pragma unroll
    for (int kk = 0; kk < 32; ++kk){
      float4 a4 = *(float4*)&As[kk][tm*4];
      float4 b4 = *(float4*)&Bs[kk][tn*4];
      float a[4] = {a4.x,a4.y,a4.z,a4.w};
      float b[4] = {b4.x,b4.y,b4.z,b4.w};
      #pragma unroll
      for (int i = 0; i < 4; ++i)
        #pragma unroll
        for (int j = 0; j < 4; ++j)
          acc[i][j] = fmaf(a[i], b[j], acc[i][j]);
    }
    __syncthreads();
  }
  #pragma unroll
  for (int i = 0; i < 4; ++i){
    int row = m0 + tm*4 + i;
    if (row <= TS){
      #pragma unroll
      for (int j = 0; j < 4; ++j)
        tab[((size_t)w*(TS+1) + row)*HH + n0 + tn*4 + j] = acc[i][j];
    }
  }
}

// pack GRU weights into MFMA B-fragment order, bf16 hi/lo planes (run once).
// Virtual gate-col groups g: 0=r, 1=z, 2=xn (K 0..255), 3=hn (K 256..511).
// layout: [ks(16)][g(4)][ct(16)][lane(64)][8 shorts]
__global__ void k_wpack(const float* __restrict__ w_ih, const float* __restrict__ w_hh,
                        short* __restrict__ wp_hi, short* __restrict__ wp_lo){
  int idx = blockIdx.x*256 + threadIdx.x;       // 65536 fragment-octets
  int lane = idx & 63;
  int rest = idx >> 6;
  int ct = rest & 15; rest >>= 4;
  int g  = rest & 3;
  int ks = rest >> 2;
  int col = ct*16 + (lane & 15);
  int kb  = ks*32 + (lane >> 4)*8;
  short hi[8], lo[8];
  #pragma unroll
  for (int j = 0; j < 8; ++j){
    int k = kb + j;
    float v;
    if      (g == 0) v = (k < 256) ? w_ih[col*HH + k]        : w_hh[col*HH + k - 256];
    else if (g == 1) v = (k < 256) ? w_ih[(256+col)*HH + k]  : w_hh[(256+col)*HH + k - 256];
    else if (g == 2) v = (k < 256) ? w_ih[(512+col)*HH + k]  : 0.0f;
    else             v = (k < 256) ? 0.0f                    : w_hh[(512+col)*HH + k - 256];
    unsigned short h = f2bf(v);
    hi[j] = (short)h;
    lo[j] = (short)f2bf(v - bf2f(h));
  }
  *(short8v*)&wp_hi[(size_t)idx*8] = *(short8v*)hi;
  *(short8v*)&wp_lo[(size_t)idx*8] = *(short8v*)lo;
}

// ---------------- per-step kernels ----------------

// ax[dst,w] = d[dst]^2 * win[dst,w] + sum_in-edges coef * win[src,w]
__global__ void k_ax(const int* __restrict__ row_start, const int* __restrict__ csr_src,
                     const float* __restrict__ csr_cf, const float* __restrict__ dval,
                     const float* __restrict__ ring, float* __restrict__ ax, int step){
  int i = blockIdx.x*256 + threadIdx.x;
  if (i >= NN*WW) return;
  int dst = i/WW, w = i - dst*WW;
  int ph = step + w; if (ph >= WW) ph -= WW;   // ring-buffer rotation
  float dv = dval[dst];
  float acc = dv*dv*ring[dst*WW + ph];
  int e1 = row_start[dst+1];
  for (int e = row_start[dst]; e < e1; ++e)
    acc += csr_cf[e]*ring[csr_src[e]*WW + ph];
  ax[i] = acc;
}

// t[n,h] = relu(ta_b[h] + sum_w lerp(tab[w], ax[n,w])[h])
__global__ __launch_bounds__(256) void k_t(const float* __restrict__ ax,
                                           const float* __restrict__ tab,
                                           const float* __restrict__ ta_b,
                                           float* __restrict__ t_out){
  __shared__ int   sidx[8][12];
  __shared__ float sfrac[8][12];
  int tid = threadIdx.x;
  int n0 = blockIdx.x*8;
  if (tid < 96){
    int r = tid/12, w = tid - r*12;
    float u = (ax[(n0+r)*WW + w] + TA) * ((float)TS/(2.0f*TA));
    u = fminf(fmaxf(u, 0.0f), (float)TS - 0.0005f);
    int i = (int)u;
    sidx[r][w] = i;
    sfrac[r][w] = u - (float)i;
  }
  __syncthreads();
  float tb = ta_b[tid];
  #pragma unroll
  for (int r = 0; r < 8; ++r){
    float acc = tb;
    #pragma unroll
    for (int w = 0; w < 12; ++w){
      const float* p = tab + ((size_t)w*(TS+1) + sidx[r][w])*HH + tid;
      float v0 = p[0], v1 = p[HH];
      acc += v0 + sfrac[r][w]*(v1 - v0);
    }
    t_out[(n0+r)*HH + tid] = acc > 0.0f ? acc : 0.0f;
  }
}

// MFMA GRU: X=[T|H] (4096x512) vs gate groups, bf16 hi/lo 3-pass split.
// Block: 32 rows x 64 gate-cols, 4 waves = 2 row-slices x 2 col-slices.
// ks 0..7: K from T (groups r,z,xn); ks 8..15: K from H (groups r,z,hn).
__global__ __launch_bounds__(256) void k_gru(const float* __restrict__ t_in,
                                             const float* __restrict__ h_in,
                                             const short* __restrict__ wp_hi,
                                             const short* __restrict__ wp_lo,
                                             const float* __restrict__ b_ih,
                                             const float* __restrict__ b_hh,
                                             float* __restrict__ h_out){
  __shared__ __align__(16) short Ah[2][2][64][8];   // [buf][row-tile][lane][8]
  __shared__ __align__(16) short Al[2][2][64][8];
  int tid = threadIdx.x;
  int nb = blockIdx.x;          // 64-col block (4 total)
  int m0 = blockIdx.y*32;       // 32-row block (128 total)
  int wv = tid >> 6, lane = tid & 63;
  int ws = wv >> 1, cs = wv & 1;         // row-slice, col-slice
  int ct0 = nb*4 + cs*2;                 // first of wave's 2 col-tiles
  // staging coords: thread loads float4 X[m0+sr][ks*32+sc4]
  int sr = tid >> 3, sc4 = (tid & 7)*4;
  int s_rt = sr >> 4;
  int s_lane = (sr & 15) + 16*(sc4 >> 3);
  int s_j = sc4 & 7;                     // 0 or 4

  f32x4 acc[4][2];
  #pragma unroll
  for (int g = 0; g < 4; ++g)
    #pragma unroll
    for (int c = 0; c < 2; ++c) acc[g][c] = (f32x4){0.f,0.f,0.f,0.f};

  const float* srow_t = t_in + (size_t)(m0+sr)*HH + sc4;
  const float* srow_h = h_in + (size_t)(m0+sr)*HH + sc4;

  // stage ks=0 into buf 0
  {
    float4 v = *(const float4*)(srow_t);
    float f[4] = {v.x,v.y,v.z,v.w};
    short h4[4], l4[4];
    #pragma unroll
    for (int j = 0; j < 4; ++j){
      unsigned short h = f2bf(f[j]);
      h4[j] = (short)h; l4[j] = (short)f2bf(f[j] - bf2f(h));
    }
    *(short4*)&Ah[0][s_rt][s_lane][s_j] = *(short4*)h4;
    *(short4*)&Al[0][s_rt][s_lane][s_j] = *(short4*)l4;
  }
  __syncthreads();

#define GRU_STEP(KS, G2, SRC_NEXT, HAVE_NEXT)                                     \
  {                                                                               \
    const int cur = (KS) & 1, nxt = cur ^ 1;                                      \
    short8v a_h = *(short8v*)&Ah[cur][ws][lane][0];                               \
    short8v a_l = *(short8v*)&Al[cur][ws][lane][0];                               \
    float4 xv;                                                                    \
    if (HAVE_NEXT) xv = *(const float4*)(SRC_NEXT);                               \
    _Pragma("unroll")                                                             \
    for (int c2 = 0; c2 < 2; ++c2){                                               \
      const size_t bbase = ((size_t)((KS)*4)*16 + (size_t)(ct0 + c2))*64 + lane;  \
      short8v b0h = *(const short8v*)&wp_hi[(bbase + (size_t)0*16*64)*8];         \
      short8v b0l = *(const short8v*)&wp_lo[(bbase + (size_t)0*16*64)*8];         \
      short8v b1h = *(const short8v*)&wp_hi[(bbase + (size_t)1*16*64)*8];         \
      short8v b1l = *(const short8v*)&wp_lo[(bbase + (size_t)1*16*64)*8];         \
      short8v b2h = *(const short8v*)&wp_hi[(bbase + (size_t)(G2)*16*64)*8];      \
      short8v b2l = *(const short8v*)&wp_lo[(bbase + (size_t)(G2)*16*64)*8];      \
      acc[0][c2] = __builtin_amdgcn_mfma_f32_16x16x32_bf16(a_h, b0h, acc[0][c2], 0,0,0); \
      acc[0][c2] = __builtin_amdgcn_mfma_f32_16x16x32_bf16(a_l, b0h, acc[0][c2], 0,0,0); \
      acc[0][c2] = __builtin_amdgcn_mfma_f32_16x16x32_bf16(a_h, b0l, acc[0][c2], 0,0,0); \
      acc[1][c2] = __builtin_amdgcn_mfma_f32_16x16x32_bf16(a_h, b1h, acc[1][c2], 0,0,0); \
      acc[1][c2] = __builtin_amdgcn_mfma_f32_16x16x32_bf16(a_l, b1h, acc[1][c2], 0,0,0); \
      acc[1][c2] = __builtin_amdgcn_mfma_f32_16x16x32_bf16(a_h, b1l, acc[1][c2], 0,0,0); \
      acc[G2][c2] = __builtin_amdgcn_mfma_f32_16x16x32_bf16(a_h, b2h, acc[G2][c2], 0,0,0); \
      acc[G2][c2] = __builtin_amdgcn_mfma_f32_16x16x32_bf16(a_l, b2h, acc[G2][c2], 0,0,0); \
      acc[G2][c2] = __builtin_amdgcn_mfma_f32_16x16x32_bf16(a_h, b2l, acc[G2][c2], 0,0,0); \
    }                                                                             \
    if (HAVE_NEXT){                                                               \
      float f[4] = {xv.x,xv.y,xv.z,xv.w};                                         \
      short h4[4], l4[4];                                                         \
      _Pragma("unroll")                                                           \
      for (int j = 0; j < 4; ++j){                                                \
        unsigned short h = f2bf(f[j]);                                            \
        h4[j] = (short)h; l4[j] = (short)f2bf(f[j] - bf2f(h));                    \
      }                                                                           \
      *(short4*)&Ah[nxt][s_rt][s_lane][s_j] = *(short4*)h4;                       \
      *(short4*)&Al[nxt][s_rt][s_lane][s_j] = *(short4*)l4;                       \
    }                                                                             \
    __syncthreads();                                                              \
  }

  #pragma unroll
  for (int ks = 0; ks < 8; ++ks)
    GRU_STEP(ks, 2, (ks+1 < 8) ? (srow_t + (ks+1)*32) : srow_h, 1)
  #pragma unroll
  for (int ks = 8; ks < 16; ++ks)
    GRU_STEP(ks, 3, srow_h + (ks+1-8)*32, (ks < 15))
#undef GRU_STEP

  // epilogue: gates + h'
  int row_base = m0 + ws*16 + ((lane >> 4) << 2);
  int col_base = nb*64 + cs*32 + (lane & 15);
  #pragma unroll
  for (int c2 = 0; c2 < 2; ++c2){
    int col = col_base + c2*16;
    float br  = b_ih[col]        + b_hh[col];
    float bz  = b_ih[col + HH]   + b_hh[col + HH];
    float bxn = b_ih[col + 2*HH];
    float bhn = b_hh[col + 2*HH];
    #pragma unroll
    for (int q = 0; q < 4; ++q){
      int row = row_base + q;
      float r = fast_sigmoid(acc[0][c2][q] + br);
      float z = fast_sigmoid(acc[1][c2][q] + bz);
      float n = fast_tanh(acc[2][c2][q] + bxn + r*(acc[3][c2][q] + bhn));
      float hv = h_in[(size_t)row*HH + col];
      h_out[(size_t)row*HH + col] = (1.0f - z)*n + z*hv;
    }
  }
}

// pred = h2 @ out_w + out_b; write output column s and the ring slot
__global__ __launch_bounds__(256) void k_pred(const float* __restrict__ h2,
                                              const float* __restrict__ out_w,
                                              const float* __restrict__ out_b,
                                              float* __restrict__ out,
                                              float* __restrict__ ring, int step){
  int gtid = blockIdx.x*256 + threadIdx.x;
  int row = gtid >> 6;
  int lane = threadIdx.x & 63;
  if (row >= NN) return;
  const float* hr = h2 + row*HH;
  float s = 0.0f;
  #pragma unroll
  for (int c = lane; c < HH; c += 64) s += hr[c]*out_w[c];
  #pragma unroll
  for (int off = 32; off > 0; off >>= 1) s += __shfl_down(s, off, 64);
  if (lane == 0){
    float p = s + out_b[0];
    out[row*PP + step] = p;
    ring[row*WW + step] = p;   // step < 12, slot step is the one rotated out
  }
}

// ---------------- launcher ----------------

extern "C" void kernel_launch(void* const* d_in, const int* in_sizes, int n_in,
                              void* d_out, int out_size, void* d_ws, size_t ws_size,
                              hipStream_t stream){
  const float* x     = (const float*)d_in[0];
  const int*   ei    = (const int*)  d_in[1];
  const float* ew    = (const float*)d_in[2];
  const float* gcn_w = (const float*)d_in[3];
  const float* ta_w  = (const float*)d_in[4];
  const float* ta_b  = (const float*)d_in[5];
  const float* w_ih  = (const float*)d_in[6];
  const float* w_hh  = (const float*)d_in[7];
  const float* b_ih  = (const float*)d_in[8];
  const float* b_hh  = (const float*)d_in[9];
  const float* out_w = (const float*)d_in[10];
  const float* out_b = (const float*)d_in[11];
  float* out = (float*)d_out;

  // tab occupies the front of ws; the setup-only buffers (hash + edge temps,
  // 4.5 MB) ALIAS into tab's 12.6 MB region — dead before k_tab runs.
  char* base = (char*)d_ws;
  float* tab = (float*)base;                               // 12*(TS+1)*HH*4 = 12.6 MB
  char* p = base;
  int*   keys    = (int*)p;   p += (size_t)HS*4;           // |
  int*   midx    = (int*)p;   p += (size_t)HS*4;           // | setup-only,
  int*   wsrc    = (int*)p;   p += (size_t)EE*4;           // | aliased inside tab
  int*   wdst    = (int*)p;   p += (size_t)EE*4;           // |
  float* wwt     = (float*)p; p += (size_t)EE*4;           // |
  float* coef    = (float*)p; p += (size_t)EE*4;           // |
  p = base + (size_t)12*(TS+1)*HH*4;                       // end of tab
  int*   csr_src = (int*)p;   p += (size_t)EE*4;
  float* csr_cf  = (float*)p; p += (size_t)EE*4;
  float* deg     = (float*)p; p += (size_t)NN*4;
  float* dval    = (float*)p; p += (size_t)NN*4;
  int*   cnt     = (int*)p;   p += (size_t)NN*4;
  int*   fill    = (int*)p;   p += (size_t)NN*4;
  int*   rowst   = (int*)p;   p += (size_t)(NN+64)*4;
  int*   count   = (int*)p;   p += 256;
  float* ring    = (float*)p; p += (size_t)NN*WW*4;
  float* ax      = (float*)p; p += (size_t)NN*WW*4;
  float* tbuf    = (float*)p; p += (size_t)NN*HH*4;
  float* hA      = (float*)p; p += (size_t)NN*HH*4;
  float* hB      = (float*)p; p += (size_t)NN*HH*4;
  short* wp_hi   = (short*)p; p += (size_t)16*4*16*64*8*2; // 1 MB
  short* wp_lo   = (short*)p; p += (size_t)16*4*16*64*8*2; // 1 MB

  k_init   <<<(NN*HH)/256, 256, 0, stream>>>(x, keys, midx, deg, cnt, ring, hA, count);
  k_insert <<<EE/256, 256, 0, stream>>>(ei, keys, midx);
  k_compact<<<EE/256, 256, 0, stream>>>(ei, ew, keys, midx, wsrc, wdst, wwt, deg, cnt, count);
  k_dfin   <<<NN/256, 256, 0, stream>>>(deg, dval);
  k_coeff  <<<EE/256, 256, 0, stream>>>(wsrc, wdst, wwt, dval, coef, count);
  k_scan   <<<1, 1024, 0, stream>>>(cnt, rowst, fill);
  k_scatter<<<EE/256, 256, 0, stream>>>(wsrc, wdst, coef, fill, csr_src, csr_cf, count);
  k_wpack  <<<256, 256, 0, stream>>>(w_ih, w_hh, wp_hi, wp_lo);
  // after k_scatter the aliased setup buffers are dead; build the table over them
  k_tab    <<<dim3(HH/64, (TS+64)/64, WW), 256, 0, stream>>>(gcn_w, ta_w, tab);

  for (int s = 0; s < PP; ++s){
    float* h_in  = (s & 1) ? hB : hA;
    float* h_out = (s & 1) ? hA : hB;
    k_ax  <<<(NN*WW)/256, 256, 0, stream>>>(rowst, csr_src, csr_cf, dval, ring, ax, s);
    k_t   <<<NN/8, 256, 0, stream>>>(ax, tab, ta_b, tbuf);
    k_gru <<<dim3(4, NN/32), 256, 0, stream>>>(tbuf, h_in, wp_hi, wp_lo, b_ih, b_hh, h_out);
    k_pred<<<NN/4, 256, 0, stream>>>(h_out, out_w, out_b, out, ring, s);
  }
}